// Round 12
// baseline (56.090 us; speedup 1.0000x reference)
//
#include <hip/hip_runtime.h>
#include <hip/hip_fp16.h>
#include <math.h>

#define NVIEW 3
#define HLOW 256
#define WLOW 256
#define NPIX (HLOW * WLOW)
#define NS 64
#define VOLN 128
#define IMGH 512
#define IMGW 512
#define BLK 256
#define NVOX (VOLN * VOLN * VOLN)      // 2097152
#define UPS2_BLOCKS ((NVIEW * IMGH * IMGW / 2) / BLK) // 1536 (2 px per thread)
#define NXCD 8

// march: 2 threads per ray (even/odd samples), 128 rays per block
#define RAYS_PER_BLOCK 128
#define BPV_MARCH (NPIX / RAYS_PER_BLOCK)        // 512 blocks per view
#define MARCH_BLOCKS (NVIEW * BPV_MARCH)         // 1536
#define CHUNK (MARCH_BLOCKS / NXCD)              // 192

// fallback march: 1 thread per ray
#define BPV_F32 (NPIX / BLK)                     // 256
#define F32_BLOCKS (NVIEW * BPV_F32)             // 768

#define LOG2E     1.4426950408889634f
#define INV_LOG2E 0.6931471805599453f

typedef _Float16 h2 __attribute__((ext_vector_type(2)));

// ---------------- per-ray setup: everything affine in SAMPLE INDEX s ------
struct Ray {
    float ax0, axs, ay0, ays, az0, azs;  // grid coords affine in s
    float sLo, sHi;                      // outside-sphere bounds in s-space
    float z0, zstep, ncz;
};

__device__ __forceinline__ Ray ray_setup(
    int view, int row, int col,
    const float* __restrict__ intrs, const float* __restrict__ c2ws,
    const float* __restrict__ nf)
{
    const float px = 511.0f * (float)col * (1.0f / 255.0f);
    const float py = 511.0f * (float)row * (1.0f / 255.0f);

    const float* K = intrs + view * 9;
    const float a = K[0], b = K[1], c = K[2];
    const float d = K[3], e = K[4], f = K[5];
    const float g = K[6], h = K[7], i9 = K[8];
    const float det = a * (e * i9 - f * h) - b * (d * i9 - f * g) + c * (d * h - e * g);
    const float id = 1.0f / det;
    const float m00 = (e * i9 - f * h) * id, m01 = -(b * i9 - c * h) * id, m02 = (b * f - c * e) * id;
    const float m10 = -(d * i9 - f * g) * id, m11 = (a * i9 - c * g) * id, m12 = -(a * f - c * d) * id;
    const float m20 = (d * h - e * g) * id, m21 = -(a * h - b * g) * id, m22 = (a * e - b * d) * id;

    const float cx = m00 * px + m01 * py + m02;
    const float cy = m10 * px + m11 * py + m12;
    const float cz = m20 * px + m21 * py + m22;
    const float inr = rsqrtf(cx * cx + cy * cy + cz * cz);
    const float ncz = cz * inr;

    const float ncx = cx * inr, ncy = cy * inr;
    const float* M = c2ws + view * 16;
    const float dx = M[0] * ncx + M[1] * ncy + M[2] * ncz;
    const float dy = M[4] * ncx + M[5] * ncy + M[6] * ncz;
    const float dz = M[8] * ncx + M[9] * ncy + M[10] * ncz;
    const float tx = M[3], ty = M[7], tz = M[11];

    const float z0 = nf[view * 2 + 0];
    const float zstep = (nf[view * 2 + 1] - z0) * (1.0f / 63.0f);

    Ray r;
    const float gx0 = (tx + 1.0f) * 63.5f, gxs = dx * 63.5f;
    const float gy0 = (ty + 1.0f) * 63.5f, gys = dy * 63.5f;
    const float gz0 = (tz + 1.0f) * 63.5f, gzs = dz * 63.5f;
    r.ax0 = fmaf(gxs, z0, gx0); r.axs = gxs * zstep;
    r.ay0 = fmaf(gys, z0, gy0); r.ays = gys * zstep;
    r.az0 = fmaf(gzs, z0, gz0); r.azs = gzs * zstep;

    const float bq = tx * dx + ty * dy + tz * dz;
    const float cq = tx * tx + ty * ty + tz * tz;
    const float disc = bq * bq - (cq - 1.0f);
    if (disc >= 0.0f) {
        const float rt = sqrtf(disc);
        const float inv = 1.0f / zstep;
        r.sLo = (-bq - rt - z0) * inv;
        r.sHi = (-bq + rt - z0) * inv;
    } else {
        r.sLo = 3.4e38f;
        r.sHi = 0.0f;
    }

    r.z0 = z0;
    r.zstep = zstep;
    r.ncz = ncz;
    return r;
}

// ---------------- build: 8B/cell packed f16 table, pre-scaled by log2(e) --
// P[z][y][x] = uint2:
//   word0 = half2( v[z ][y][x], v[z ][y+1][x] )  (y-pair at z)
//   word1 = half2( v[z+1][y][x], v[z+1][y+1][x] ) (y-pair at z+1)
// The march reads cells x and x+1 with ONE 16B (8B-aligned) load.
__global__ __launch_bounds__(BLK) void build_pack8_kernel(
    const float* __restrict__ vol, uint2* __restrict__ P)
{
    const int id = blockIdx.x * BLK + threadIdx.x;
    const int x = id & 127;
    const int y = (id >> 7) & 127;
    const int z = id >> 14;
    const int yp = min(y + 1, 127);
    const int zp = min(z + 1, 127);

    const float v00 = vol[(z  * VOLN + y ) * VOLN + x];
    const float v01 = vol[(z  * VOLN + yp) * VOLN + x];
    const float v10 = vol[(zp * VOLN + y ) * VOLN + x];
    const float v11 = vol[(zp * VOLN + yp) * VOLN + x];

    const __half2 w0 = __floats2half2_rn(v00 * LOG2E, v01 * LOG2E);
    const __half2 w1 = __floats2half2_rn(v10 * LOG2E, v11 * LOG2E);
    uint2 o;
    o.x = *reinterpret_cast<const unsigned*>(&w0);
    o.y = *reinterpret_cast<const unsigned*>(&w1);
    P[id] = o;
}

// ---------------- raymarch: pack8, 2 threads/ray, 2-deep pipeline ---------
__global__ __launch_bounds__(BLK) void raymarch_pack8_kernel(
    const float* __restrict__ intrs, const float* __restrict__ c2ws,
    const float* __restrict__ nf, const char* __restrict__ Fb,
    float* __restrict__ depth_low, float* __restrict__ partials)
{
    const int wg  = blockIdx.x;
    const int swz = (wg & (NXCD - 1)) * CHUNK + (wg >> 3); // bijective, 1536=8*192
    const int view = swz / BPV_MARCH;
    const int rb   = swz - view * BPV_MARCH;   // ray-block within view
    const int t    = threadIdx.x;
    const int rloc = t >> 1;                   // ray within block
    const int par  = t & 1;                    // even/odd sample parity
    const int ray  = rb * RAYS_PER_BLOCK + rloc;
    const int row  = ray >> 8;
    const int col  = ray & 255;

    const Ray r = ray_setup(view, row, col, intrs, c2ws, nf);

    // closed-form outside-sample count (per ray; only par==0 contributes)
    const float ilo = ceilf(fmaxf(r.sLo, 0.0f));
    const float ihi = floorf(fminf(r.sHi, 63.0f));
    const float cnt = 64.0f - fmaxf(0.0f, ihi - ilo + 1.0f);
    const float parf = (float)par;

    float lsum = 0.0f, sacc = 0.0f, d6 = 0.0f, dout = 0.0f;

    h2 fx2[2][8], fyw[2][8];              // fyw = (1-fy, fy)
    float fzs[2][8];
    uint4 q[2][8];

// thread's samples: s = SB + 2*i + par, SB = 16*b, i = 0..7
#define ADDR_BATCH(BK, SB)                                                    \
    {                                                                         \
        unsigned offs[8];                                                     \
        _Pragma("unroll")                                                     \
        for (int i = 0; i < 8; ++i) {                                         \
            const float sf = (float)((SB) + 2 * i) + parf;                    \
            float gx = fmaf(r.axs, sf, r.ax0);                                \
            float gy = fmaf(r.ays, sf, r.ay0);                                \
            float gz = fmaf(r.azs, sf, r.az0);                                \
            gx = fminf(fmaxf(gx, 0.0f), 126.9995f);                           \
            gy = fminf(fmaxf(gy, 0.0f), 126.9995f);                           \
            gz = fminf(fmaxf(gz, 0.0f), 126.9995f);                           \
            const float xbf = floorf(gx);                                     \
            const float ybf = floorf(gy);                                     \
            const float zbf = floorf(gz);                                     \
            const float fx = gx - xbf;                                        \
            const float fy = gy - ybf;                                        \
            fzs[BK][i] = gz - zbf;                                            \
            fx2[BK][i] = (h2){(_Float16)fx, (_Float16)fx};                    \
            fyw[BK][i] = (h2){(_Float16)(1.0f - fy), (_Float16)fy};           \
            offs[i] = (unsigned)fmaf(zbf, 16384.0f, fmaf(ybf, 128.0f, xbf));  \
        }                                                                     \
        _Pragma("unroll")                                                     \
        for (int i = 0; i < 8; ++i)                                           \
            q[BK][i] = *reinterpret_cast<const uint4*>(Fb + (size_t)offs[i] * 8); \
    }

// q = [ypair(x,z0), ypair(x,z1), ypair(x+1,z0), ypair(x+1,z1)]
#define CONSUME_BATCH(BK, SB)                                                 \
    _Pragma("unroll")                                                         \
    for (int i = 0; i < 8; ++i) {                                             \
        const float sf = (float)((SB) + 2 * i) + parf;                        \
        const h2 w0 = __builtin_bit_cast(h2, q[BK][i].x);                     \
        const h2 w1 = __builtin_bit_cast(h2, q[BK][i].y);                     \
        const h2 w2 = __builtin_bit_cast(h2, q[BK][i].z);                     \
        const h2 w3 = __builtin_bit_cast(h2, q[BK][i].w);                     \
        const h2 cx0 = fx2[BK][i] * (w2 - w0) + w0;   /* x-lerp @ z0 */       \
        const h2 cx1 = fx2[BK][i] * (w3 - w1) + w1;   /* x-lerp @ z1 */       \
        const float c0 = __builtin_amdgcn_fdot2(cx0, fyw[BK][i], 0.0f, false);\
        const float c1 = __builtin_amdgcn_fdot2(cx1, fyw[BK][i], 0.0f, false);\
        const float dens = fmaf(fzs[BK][i], c1 - c0, c0); /* log2e*rho */     \
        const float w = exp2f(dens);                      /* = e^rho */       \
        lsum += w;                                                            \
        sacc = fmaf(sf, w, sacc);                                             \
        if ((SB) == 0 && i < 3) d6 += dens;   /* s=2i+par<6 <=> i<3 */        \
        const bool o = (sf < r.sLo) || (sf > r.sHi);                          \
        dout += o ? dens : 0.0f;                                              \
    }

    // 4 batches of 8 samples each (32 per thread), 2-deep pipeline
    ADDR_BATCH(0, 0)
    ADDR_BATCH(1, 16)
    CONSUME_BATCH(0, 0)
    ADDR_BATCH(0, 32)
    CONSUME_BATCH(1, 16)
    ADDR_BATCH(1, 48)
    CONSUME_BATCH(0, 32)
    CONSUME_BATCH(1, 48)
#undef ADDR_BATCH
#undef CONSUME_BATCH

    // merge even/odd halves within the lane pair
    lsum += __shfl_xor(lsum, 1);
    sacc += __shfl_xor(sacc, 1);
    if (par == 0)
        depth_low[view * NPIX + ray] =
            fmaf(r.zstep, sacc / lsum, r.z0) * r.ncz;

    __shared__ float s0[BLK], s1[BLK], s2[BLK];
    s0[t] = d6; s1[t] = dout; s2[t] = par ? 0.0f : cnt;
    __syncthreads();
    for (int off = BLK / 2; off > 0; off >>= 1) {
        if (t < off) {
            s0[t] += s0[t + off];
            s1[t] += s1[t + off];
            s2[t] += s2[t + off];
        }
        __syncthreads();
    }
    if (t == 0) {
        partials[swz * 3 + 0] = s0[0] * INV_LOG2E;   // un-scale linear sums
        partials[swz * 3 + 1] = s1[0] * INV_LOG2E;
        partials[swz * 3 + 2] = s2[0];
    }
}

// ---------------- fallback raymarch: f32 volume direct (tiny ws) ----------
__global__ __launch_bounds__(BLK) void raymarch_f32_kernel(
    const float* __restrict__ intrs, const float* __restrict__ c2ws,
    const float* __restrict__ nf, const float* __restrict__ vol,
    float* __restrict__ depth_low, float* __restrict__ partials)
{
    const int view = blockIdx.x >> 8;
    const int row  = blockIdx.x & 255;
    const int t    = threadIdx.x;

    const Ray r = ray_setup(view, row, t, intrs, c2ws, nf);

    const float ilo = ceilf(fmaxf(r.sLo, 0.0f));
    const float ihi = floorf(fminf(r.sHi, 63.0f));
    const float cnt = 64.0f - fmaxf(0.0f, ihi - ilo + 1.0f);

    float lsum = 0.0f, sacc = 0.0f, d6 = 0.0f, dout = 0.0f;

    #pragma unroll 16
    for (int s = 0; s < NS; ++s) {
        const float sf = (float)s;
        float gx = fmaf(r.axs, sf, r.ax0);
        float gy = fmaf(r.ays, sf, r.ay0);
        float gz = fmaf(r.azs, sf, r.az0);
        gx = fminf(fmaxf(gx, 0.0f), 126.9995f);
        gy = fminf(fmaxf(gy, 0.0f), 126.9995f);
        gz = fminf(fmaxf(gz, 0.0f), 126.9995f);
        const float xbf = floorf(gx);
        const float ybf = floorf(gy);
        const float zbf = floorf(gz);
        const float fx = gx - xbf, fy = gy - ybf, fz = gz - zbf;
        const unsigned off = (unsigned)fmaf(zbf, 16384.0f, fmaf(ybf, 128.0f, xbf));

        const float* p0 = vol + off;
        const float2 v00 = *reinterpret_cast<const float2*>(p0);
        const float2 v01 = *reinterpret_cast<const float2*>(p0 + VOLN);
        const float2 v10 = *reinterpret_cast<const float2*>(p0 + VOLN * VOLN);
        const float2 v11 = *reinterpret_cast<const float2*>(p0 + VOLN * VOLN + VOLN);

        const float c00 = fmaf(fx, v00.y - v00.x, v00.x);
        const float c01 = fmaf(fx, v01.y - v01.x, v01.x);
        const float c10 = fmaf(fx, v10.y - v10.x, v10.x);
        const float c11 = fmaf(fx, v11.y - v11.x, v11.x);
        const float c0 = fmaf(fy, c01 - c00, c00);
        const float c1 = fmaf(fy, c11 - c10, c10);
        const float dens = fmaf(fz, c1 - c0, c0);

        const float w = __expf(dens);
        lsum += w;
        sacc = fmaf(sf, w, sacc);

        if (s < 6) d6 += dens;
        const bool o = (sf < r.sLo) || (sf > r.sHi);
        dout += o ? dens : 0.0f;
    }

    depth_low[view * NPIX + row * WLOW + t] =
        fmaf(r.zstep, sacc / lsum, r.z0) * r.ncz;

    __shared__ float s0[BLK], s1[BLK], s2[BLK];
    s0[t] = d6; s1[t] = dout; s2[t] = cnt;
    __syncthreads();
    for (int off = BLK / 2; off > 0; off >>= 1) {
        if (t < off) {
            s0[t] += s0[t + off];
            s1[t] += s1[t + off];
            s2[t] += s2[t + off];
        }
        __syncthreads();
    }
    if (t == 0) {
        partials[blockIdx.x * 3 + 0] = s0[0];
        partials[blockIdx.x * 3 + 1] = s1[0];
        partials[blockIdx.x * 3 + 2] = s2[0];
    }
}

// ---------------- fused epilogue: upsample (2 px/thread) + occ reduce ----
// nppv = partial-blocks per view (512 main path, 256 fallback)
__global__ __launch_bounds__(BLK) void epilogue_kernel(
    const float* __restrict__ low, const float* __restrict__ partials,
    float* __restrict__ out, int nppv)
{
    if (blockIdx.x >= UPS2_BLOCKS) {
        const int view = blockIdx.x - UPS2_BLOCKS;
        const int t = threadIdx.x;
        __shared__ float s0[BLK], s1[BLK], s2[BLK];
        float a0 = 0.0f, a1 = 0.0f, a2 = 0.0f;
        for (int k = t; k < nppv; k += BLK) {
            const int bi = view * nppv + k;
            a0 += partials[bi * 3 + 0];
            a1 += partials[bi * 3 + 1];
            a2 += partials[bi * 3 + 2];
        }
        s0[t] = a0; s1[t] = a1; s2[t] = a2;
        __syncthreads();
        for (int off = BLK / 2; off > 0; off >>= 1) {
            if (t < off) {
                s0[t] += s0[t + off];
                s1[t] += s1[t + off];
                s2[t] += s2[t + off];
            }
            __syncthreads();
        }
        if (t == 0) {
            out[NVIEW * IMGH * IMGW + view] =
                s0[0] * (1.0f / (float)(NPIX * 6)) + s1[0] / (s2[0] + 1e-10f);
        }
        return;
    }

    const int idx2 = blockIdx.x * BLK + threadIdx.x;
    const int view = idx2 / (IMGH * IMGW / 2);
    const int rem  = idx2 - view * (IMGH * IMGW / 2);
    const int rr = rem >> 8;
    const int cp = rem & 255;
    const int cc0 = cp * 2;

    const float sy = (float)rr * 0.5f - 0.25f;
    const float y0f = floorf(sy);
    const float wy = sy - y0f;
    const int y0 = (int)y0f;
    const int y0c = max(y0, 0), y1c = min(y0 + 1, HLOW - 1);
    const float* src = low + view * NPIX;
    const float* r0 = src + y0c * WLOW;
    const float* r1 = src + y1c * WLOW;

    float2 res;
    {
        const float sx = (float)cc0 * 0.5f - 0.25f;
        const float x0f = floorf(sx);
        const float wx = sx - x0f;
        const int x0 = (int)x0f;
        const int x0c = max(x0, 0), x1c = min(x0 + 1, WLOW - 1);
        const float top = r0[x0c] * (1.0f - wx) + r0[x1c] * wx;
        const float bot = r1[x0c] * (1.0f - wx) + r1[x1c] * wx;
        res.x = top * (1.0f - wy) + bot * wy;
    }
    {
        const int cc1 = cc0 + 1;
        const float sx = (float)cc1 * 0.5f - 0.25f;
        const float x0f = floorf(sx);
        const float wx = sx - x0f;
        const int x0 = (int)x0f;
        const int x0c = max(x0, 0), x1c = min(x0 + 1, WLOW - 1);
        const float top = r0[x0c] * (1.0f - wx) + r0[x1c] * wx;
        const float bot = r1[x0c] * (1.0f - wx) + r1[x1c] * wx;
        res.y = top * (1.0f - wy) + bot * wy;
    }
    *reinterpret_cast<float2*>(out + view * (IMGH * IMGW) + rr * IMGW + cc0) = res;
}

extern "C" void kernel_launch(void* const* d_in, const int* in_sizes, int n_in,
                              void* d_out, int out_size, void* d_ws, size_t ws_size,
                              hipStream_t stream) {
    // input order: imgs, intrs, c2ws, near_fars, density_volume, stage_idx
    const float* intrs = (const float*)d_in[1];
    const float* c2ws  = (const float*)d_in[2];
    const float* nf    = (const float*)d_in[3];
    const float* vol   = (const float*)d_in[4];
    float* out = (float*)d_out;

    const size_t pack_bytes  = (size_t)NVOX * 8 + 16;   // +16: x=126 load tail
    const size_t depth_bytes = (size_t)NVIEW * NPIX * 4;
    const size_t part_bytes  = (size_t)MARCH_BLOCKS * 3 * 4;
    char* ws = (char*)d_ws;

    float* depth_low;
    float* partials;

    if (ws_size >= pack_bytes + depth_bytes + part_bytes) {
        uint2* P = (uint2*)ws;
        depth_low = (float*)(ws + pack_bytes);
        partials  = depth_low + NVIEW * NPIX;
        build_pack8_kernel<<<NVOX / BLK, BLK, 0, stream>>>(vol, P);
        raymarch_pack8_kernel<<<MARCH_BLOCKS, BLK, 0, stream>>>(
            intrs, c2ws, nf, (const char*)ws, depth_low, partials);
        epilogue_kernel<<<UPS2_BLOCKS + NVIEW, BLK, 0, stream>>>(
            depth_low, partials, out, BPV_MARCH);
    } else {
        depth_low = (float*)ws;
        partials  = depth_low + NVIEW * NPIX;
        raymarch_f32_kernel<<<F32_BLOCKS, BLK, 0, stream>>>(
            intrs, c2ws, nf, vol, depth_low, partials);
        epilogue_kernel<<<UPS2_BLOCKS + NVIEW, BLK, 0, stream>>>(
            depth_low, partials, out, BPV_F32);
    }
}

// Round 14
// 34.788 us; speedup vs baseline: 1.6123x; 1.6123x over previous
//
#include <hip/hip_runtime.h>
#include <hip/hip_fp16.h>
#include <math.h>

#define NVIEW 3
#define HLOW 256
#define WLOW 256
#define NPIX (HLOW * WLOW)
#define NS 64
#define VOLN 128
#define IMGH 512
#define IMGW 512
#define BLK 256
#define BLOCKS_PER_VIEW (NPIX / BLK)   // 256 (one block per low-res row)
#define NVOX (VOLN * VOLN * VOLN)      // 2097152
#define UPS2_BLOCKS ((NVIEW * IMGH * IMGW / 2) / BLK) // 1536 (2 px per thread)
#define NXCD 8
#define MARCH_BLOCKS (NVIEW * BLOCKS_PER_VIEW)        // 768
#define CHUNK (MARCH_BLOCKS / NXCD)                   // 96

#define LOG2E     1.4426950408889634f
#define INV_LOG2E 0.6931471805599453f

typedef _Float16 h2 __attribute__((ext_vector_type(2)));

// ---------------- per-ray setup: everything affine in SAMPLE INDEX s ------
struct Ray {
    float ax0, axs, ay0, ays, az0, azs;  // grid coords affine in s
    float sLo, sHi;                      // outside-sphere bounds in s-space
    float z0, zstep, ncz;
};

__device__ __forceinline__ Ray ray_setup(
    int view, int row, int col,
    const float* __restrict__ intrs, const float* __restrict__ c2ws,
    const float* __restrict__ nf)
{
    const float px = 511.0f * (float)col * (1.0f / 255.0f);
    const float py = 511.0f * (float)row * (1.0f / 255.0f);

    const float* K = intrs + view * 9;
    const float a = K[0], b = K[1], c = K[2];
    const float d = K[3], e = K[4], f = K[5];
    const float g = K[6], h = K[7], i9 = K[8];
    const float det = a * (e * i9 - f * h) - b * (d * i9 - f * g) + c * (d * h - e * g);
    const float id = 1.0f / det;
    const float m00 = (e * i9 - f * h) * id, m01 = -(b * i9 - c * h) * id, m02 = (b * f - c * e) * id;
    const float m10 = -(d * i9 - f * g) * id, m11 = (a * i9 - c * g) * id, m12 = -(a * f - c * d) * id;
    const float m20 = (d * h - e * g) * id, m21 = -(a * h - b * g) * id, m22 = (a * e - b * d) * id;

    const float cx = m00 * px + m01 * py + m02;
    const float cy = m10 * px + m11 * py + m12;
    const float cz = m20 * px + m21 * py + m22;
    const float inr = rsqrtf(cx * cx + cy * cy + cz * cz);
    const float ncz = cz * inr;

    const float ncx = cx * inr, ncy = cy * inr;
    const float* M = c2ws + view * 16;
    const float dx = M[0] * ncx + M[1] * ncy + M[2] * ncz;
    const float dy = M[4] * ncx + M[5] * ncy + M[6] * ncz;
    const float dz = M[8] * ncx + M[9] * ncy + M[10] * ncz;
    const float tx = M[3], ty = M[7], tz = M[11];

    const float z0 = nf[view * 2 + 0];
    const float zstep = (nf[view * 2 + 1] - z0) * (1.0f / 63.0f);

    Ray r;
    const float gx0 = (tx + 1.0f) * 63.5f, gxs = dx * 63.5f;
    const float gy0 = (ty + 1.0f) * 63.5f, gys = dy * 63.5f;
    const float gz0 = (tz + 1.0f) * 63.5f, gzs = dz * 63.5f;
    r.ax0 = fmaf(gxs, z0, gx0); r.axs = gxs * zstep;
    r.ay0 = fmaf(gys, z0, gy0); r.ays = gys * zstep;
    r.az0 = fmaf(gzs, z0, gz0); r.azs = gzs * zstep;

    const float bq = tx * dx + ty * dy + tz * dz;
    const float cq = tx * tx + ty * ty + tz * tz;
    const float disc = bq * bq - (cq - 1.0f);
    if (disc >= 0.0f) {
        const float rt = sqrtf(disc);
        const float inv = 1.0f / zstep;
        r.sLo = (-bq - rt - z0) * inv;
        r.sHi = (-bq + rt - z0) * inv;
    } else {
        r.sLo = 3.4e38f;
        r.sHi = 0.0f;
    }

    r.z0 = z0;
    r.zstep = zstep;
    r.ncz = ncz;
    return r;
}

// ---------------- build: 8B/cell packed f16 table, pre-scaled by log2(e) --
// P[z][y][x] = uint2:
//   word0 = half2( v[z ][y][x], v[z ][y+1][x] )  (y-pair at z)
//   word1 = half2( v[z+1][y][x], v[z+1][y+1][x] ) (y-pair at z+1)
// The march reads cells x and x+1 with ONE 16B (8B-aligned) load.
__global__ __launch_bounds__(BLK) void build_pack8_kernel(
    const float* __restrict__ vol, uint2* __restrict__ P)
{
    const int id = blockIdx.x * BLK + threadIdx.x;
    const int x = id & 127;
    const int y = (id >> 7) & 127;
    const int z = id >> 14;
    const int yp = min(y + 1, 127);
    const int zp = min(z + 1, 127);

    const float v00 = vol[(z  * VOLN + y ) * VOLN + x];
    const float v01 = vol[(z  * VOLN + yp) * VOLN + x];
    const float v10 = vol[(zp * VOLN + y ) * VOLN + x];
    const float v11 = vol[(zp * VOLN + yp) * VOLN + x];

    const __half2 w0 = __floats2half2_rn(v00 * LOG2E, v01 * LOG2E);
    const __half2 w1 = __floats2half2_rn(v10 * LOG2E, v11 * LOG2E);
    uint2 o;
    o.x = *reinterpret_cast<const unsigned*>(&w0);
    o.y = *reinterpret_cast<const unsigned*>(&w1);
    P[id] = o;
}

// ---------------- raymarch: pack8, 2-deep pipeline, dot2 y-lerp -----------
__global__ __launch_bounds__(BLK) void raymarch_pack8_kernel(
    const float* __restrict__ intrs, const float* __restrict__ c2ws,
    const float* __restrict__ nf, const char* __restrict__ Fb,
    float* __restrict__ depth_low, float* __restrict__ partials)
{
    const int wg  = blockIdx.x;
    const int swz = (wg & (NXCD - 1)) * CHUNK + (wg >> 3); // bijective, 768=8*96
    const int view = swz >> 8;
    const int row  = swz & 255;
    const int t    = threadIdx.x;

    const Ray r = ray_setup(view, row, t, intrs, c2ws, nf);

    // closed-form outside-sample count
    const float ilo = ceilf(fmaxf(r.sLo, 0.0f));
    const float ihi = floorf(fminf(r.sHi, 63.0f));
    const float cnt = 64.0f - fmaxf(0.0f, ihi - ilo + 1.0f);

    float lsum = 0.0f, sacc = 0.0f, d6 = 0.0f, dout = 0.0f;

    h2 fx2[2][8], fyw[2][8];              // fyw = (1-fy, fy)
    float fzs[2][8];
    uint4 q[2][8];

// compute addresses + frac vectors + issue 8 (16B, 8B-aligned) loads
#define ADDR_BATCH(BK, SB)                                                    \
    {                                                                         \
        unsigned offs[8];                                                     \
        _Pragma("unroll")                                                     \
        for (int i = 0; i < 8; ++i) {                                         \
            const float sf = (float)((SB) + i);                               \
            float gx = fmaf(r.axs, sf, r.ax0);                                \
            float gy = fmaf(r.ays, sf, r.ay0);                                \
            float gz = fmaf(r.azs, sf, r.az0);                                \
            gx = fminf(fmaxf(gx, 0.0f), 126.9995f);                           \
            gy = fminf(fmaxf(gy, 0.0f), 126.9995f);                           \
            gz = fminf(fmaxf(gz, 0.0f), 126.9995f);                           \
            const float xbf = floorf(gx);                                     \
            const float ybf = floorf(gy);                                     \
            const float zbf = floorf(gz);                                     \
            const float fx = gx - xbf;                                        \
            const float fy = gy - ybf;                                        \
            fzs[BK][i] = gz - zbf;                                            \
            fx2[BK][i] = (h2){(_Float16)fx, (_Float16)fx};                    \
            fyw[BK][i] = (h2){(_Float16)(1.0f - fy), (_Float16)fy};           \
            offs[i] = (unsigned)fmaf(zbf, 16384.0f, fmaf(ybf, 128.0f, xbf));  \
        }                                                                     \
        _Pragma("unroll")                                                     \
        for (int i = 0; i < 8; ++i)                                           \
            q[BK][i] = *reinterpret_cast<const uint4*>(Fb + (size_t)offs[i] * 8); \
    }

// q = [ypair(x,z0), ypair(x,z1), ypair(x+1,z0), ypair(x+1,z1)]
#define CONSUME_BATCH(BK, SB)                                                 \
    _Pragma("unroll")                                                         \
    for (int i = 0; i < 8; ++i) {                                             \
        const float sf = (float)((SB) + i);                                   \
        const h2 w0 = __builtin_bit_cast(h2, q[BK][i].x);                     \
        const h2 w1 = __builtin_bit_cast(h2, q[BK][i].y);                     \
        const h2 w2 = __builtin_bit_cast(h2, q[BK][i].z);                     \
        const h2 w3 = __builtin_bit_cast(h2, q[BK][i].w);                     \
        const h2 cx0 = fx2[BK][i] * (w2 - w0) + w0;   /* x-lerp @ z0 */       \
        const h2 cx1 = fx2[BK][i] * (w3 - w1) + w1;   /* x-lerp @ z1 */       \
        const float c0 = __builtin_amdgcn_fdot2(cx0, fyw[BK][i], 0.0f, false);\
        const float c1 = __builtin_amdgcn_fdot2(cx1, fyw[BK][i], 0.0f, false);\
        const float dens = fmaf(fzs[BK][i], c1 - c0, c0); /* log2e*rho */     \
        const float w = exp2f(dens);                      /* = e^rho */       \
        lsum += w;                                                            \
        sacc = fmaf(sf, w, sacc);                                             \
        if ((SB) == 0 && i < 6) d6 += dens;                                   \
        const bool o = (sf < r.sLo) || (sf > r.sHi);                          \
        dout += o ? dens : 0.0f;                                              \
    }

    ADDR_BATCH(0, 0)
    #pragma unroll
    for (int b = 0; b < 8; ++b) {
        if (b < 7) {                       // issue next batch before consuming
            if (b & 1) { ADDR_BATCH(0, (b + 1) * 8) }
            else       { ADDR_BATCH(1, (b + 1) * 8) }
        }
        if (b & 1) { CONSUME_BATCH(1, b * 8) }
        else       { CONSUME_BATCH(0, b * 8) }
    }
#undef ADDR_BATCH
#undef CONSUME_BATCH

    depth_low[view * NPIX + row * WLOW + t] =
        fmaf(r.zstep, sacc / lsum, r.z0) * r.ncz;

    __shared__ float s0[BLK], s1[BLK], s2[BLK];
    s0[t] = d6; s1[t] = dout; s2[t] = cnt;
    __syncthreads();
    for (int off = BLK / 2; off > 0; off >>= 1) {
        if (t < off) {
            s0[t] += s0[t + off];
            s1[t] += s1[t + off];
            s2[t] += s2[t + off];
        }
        __syncthreads();
    }
    if (t == 0) {
        partials[swz * 3 + 0] = s0[0] * INV_LOG2E;   // un-scale linear sums
        partials[swz * 3 + 1] = s1[0] * INV_LOG2E;
        partials[swz * 3 + 2] = s2[0];
    }
}

// ---------------- fallback raymarch: f32 volume direct (tiny ws) ----------
__global__ __launch_bounds__(BLK) void raymarch_f32_kernel(
    const float* __restrict__ intrs, const float* __restrict__ c2ws,
    const float* __restrict__ nf, const float* __restrict__ vol,
    float* __restrict__ depth_low, float* __restrict__ partials)
{
    const int view = blockIdx.x >> 8;
    const int row  = blockIdx.x & 255;
    const int t    = threadIdx.x;

    const Ray r = ray_setup(view, row, t, intrs, c2ws, nf);

    const float ilo = ceilf(fmaxf(r.sLo, 0.0f));
    const float ihi = floorf(fminf(r.sHi, 63.0f));
    const float cnt = 64.0f - fmaxf(0.0f, ihi - ilo + 1.0f);

    float lsum = 0.0f, sacc = 0.0f, d6 = 0.0f, dout = 0.0f;

    #pragma unroll 16
    for (int s = 0; s < NS; ++s) {
        const float sf = (float)s;
        float gx = fmaf(r.axs, sf, r.ax0);
        float gy = fmaf(r.ays, sf, r.ay0);
        float gz = fmaf(r.azs, sf, r.az0);
        gx = fminf(fmaxf(gx, 0.0f), 126.9995f);
        gy = fminf(fmaxf(gy, 0.0f), 126.9995f);
        gz = fminf(fmaxf(gz, 0.0f), 126.9995f);
        const float xbf = floorf(gx);
        const float ybf = floorf(gy);
        const float zbf = floorf(gz);
        const float fx = gx - xbf, fy = gy - ybf, fz = gz - zbf;
        const unsigned off = (unsigned)fmaf(zbf, 16384.0f, fmaf(ybf, 128.0f, xbf));

        const float* p0 = vol + off;
        const float2 v00 = *reinterpret_cast<const float2*>(p0);
        const float2 v01 = *reinterpret_cast<const float2*>(p0 + VOLN);
        const float2 v10 = *reinterpret_cast<const float2*>(p0 + VOLN * VOLN);
        const float2 v11 = *reinterpret_cast<const float2*>(p0 + VOLN * VOLN + VOLN);

        const float c00 = fmaf(fx, v00.y - v00.x, v00.x);
        const float c01 = fmaf(fx, v01.y - v01.x, v01.x);
        const float c10 = fmaf(fx, v10.y - v10.x, v10.x);
        const float c11 = fmaf(fx, v11.y - v11.x, v11.x);
        const float c0 = fmaf(fy, c01 - c00, c00);
        const float c1 = fmaf(fy, c11 - c10, c10);
        const float dens = fmaf(fz, c1 - c0, c0);

        const float w = __expf(dens);
        lsum += w;
        sacc = fmaf(sf, w, sacc);

        if (s < 6) d6 += dens;
        const bool o = (sf < r.sLo) || (sf > r.sHi);
        dout += o ? dens : 0.0f;
    }

    depth_low[view * NPIX + row * WLOW + t] =
        fmaf(r.zstep, sacc / lsum, r.z0) * r.ncz;

    __shared__ float s0[BLK], s1[BLK], s2[BLK];
    s0[t] = d6; s1[t] = dout; s2[t] = cnt;
    __syncthreads();
    for (int off = BLK / 2; off > 0; off >>= 1) {
        if (t < off) {
            s0[t] += s0[t + off];
            s1[t] += s1[t + off];
            s2[t] += s2[t + off];
        }
        __syncthreads();
    }
    if (t == 0) {
        partials[blockIdx.x * 3 + 0] = s0[0];
        partials[blockIdx.x * 3 + 1] = s1[0];
        partials[blockIdx.x * 3 + 2] = s2[0];
    }
}

// ---------------- fused epilogue: upsample (2 px/thread) + occ reduce ----
__global__ __launch_bounds__(BLK) void epilogue_kernel(
    const float* __restrict__ low, const float* __restrict__ partials,
    float* __restrict__ out)
{
    if (blockIdx.x >= UPS2_BLOCKS) {
        const int view = blockIdx.x - UPS2_BLOCKS;
        const int t = threadIdx.x;
        __shared__ float s0[BLK], s1[BLK], s2[BLK];
        const int bi = view * BLOCKS_PER_VIEW + t; // BLOCKS_PER_VIEW == BLK
        s0[t] = partials[bi * 3 + 0];
        s1[t] = partials[bi * 3 + 1];
        s2[t] = partials[bi * 3 + 2];
        __syncthreads();
        for (int off = BLK / 2; off > 0; off >>= 1) {
            if (t < off) {
                s0[t] += s0[t + off];
                s1[t] += s1[t + off];
                s2[t] += s2[t + off];
            }
            __syncthreads();
        }
        if (t == 0) {
            out[NVIEW * IMGH * IMGW + view] =
                s0[0] * (1.0f / (float)(NPIX * 6)) + s1[0] / (s2[0] + 1e-10f);
        }
        return;
    }

    const int idx2 = blockIdx.x * BLK + threadIdx.x;
    const int view = idx2 / (IMGH * IMGW / 2);
    const int rem  = idx2 - view * (IMGH * IMGW / 2);
    const int rr = rem >> 8;
    const int cp = rem & 255;
    const int cc0 = cp * 2;

    const float sy = (float)rr * 0.5f - 0.25f;
    const float y0f = floorf(sy);
    const float wy = sy - y0f;
    const int y0 = (int)y0f;
    const int y0c = max(y0, 0), y1c = min(y0 + 1, HLOW - 1);
    const float* src = low + view * NPIX;
    const float* r0 = src + y0c * WLOW;
    const float* r1 = src + y1c * WLOW;

    float2 res;
    {
        const float sx = (float)cc0 * 0.5f - 0.25f;
        const float x0f = floorf(sx);
        const float wx = sx - x0f;
        const int x0 = (int)x0f;
        const int x0c = max(x0, 0), x1c = min(x0 + 1, WLOW - 1);
        const float top = r0[x0c] * (1.0f - wx) + r0[x1c] * wx;
        const float bot = r1[x0c] * (1.0f - wx) + r1[x1c] * wx;
        res.x = top * (1.0f - wy) + bot * wy;
    }
    {
        const int cc1 = cc0 + 1;
        const float sx = (float)cc1 * 0.5f - 0.25f;
        const float x0f = floorf(sx);
        const float wx = sx - x0f;
        const int x0 = (int)x0f;
        const int x0c = max(x0, 0), x1c = min(x0 + 1, WLOW - 1);
        const float top = r0[x0c] * (1.0f - wx) + r0[x1c] * wx;
        const float bot = r1[x0c] * (1.0f - wx) + r1[x1c] * wx;
        res.y = top * (1.0f - wy) + bot * wy;
    }
    *reinterpret_cast<float2*>(out + view * (IMGH * IMGW) + rr * IMGW + cc0) = res;
}

extern "C" void kernel_launch(void* const* d_in, const int* in_sizes, int n_in,
                              void* d_out, int out_size, void* d_ws, size_t ws_size,
                              hipStream_t stream) {
    // input order: imgs, intrs, c2ws, near_fars, density_volume, stage_idx
    const float* intrs = (const float*)d_in[1];
    const float* c2ws  = (const float*)d_in[2];
    const float* nf    = (const float*)d_in[3];
    const float* vol   = (const float*)d_in[4];
    float* out = (float*)d_out;

    const size_t pack_bytes  = (size_t)NVOX * 8 + 16;   // +16: x=126 load tail
    const size_t depth_bytes = (size_t)NVIEW * NPIX * 4;
    const size_t part_bytes  = (size_t)NVIEW * BLOCKS_PER_VIEW * 3 * 4;
    char* ws = (char*)d_ws;

    float* depth_low;
    float* partials;

    if (ws_size >= pack_bytes + depth_bytes + part_bytes) {
        uint2* P = (uint2*)ws;
        depth_low = (float*)(ws + pack_bytes);
        partials  = depth_low + NVIEW * NPIX;
        build_pack8_kernel<<<NVOX / BLK, BLK, 0, stream>>>(vol, P);
        raymarch_pack8_kernel<<<MARCH_BLOCKS, BLK, 0, stream>>>(
            intrs, c2ws, nf, (const char*)ws, depth_low, partials);
    } else {
        depth_low = (float*)ws;
        partials  = depth_low + NVIEW * NPIX;
        raymarch_f32_kernel<<<MARCH_BLOCKS, BLK, 0, stream>>>(
            intrs, c2ws, nf, vol, depth_low, partials);
    }

    epilogue_kernel<<<UPS2_BLOCKS + NVIEW, BLK, 0, stream>>>(depth_low, partials, out);
}